// Round 7
// baseline (24.049 us; speedup 1.0000x reference)
//
#include <hip/hip_runtime.h>
#include <cmath>

// ---------------- problem constants (idx = 0) ----------------
#define S_    80
#define NBAT  16
#define NA_   3
#define NCH_  255          // NB * (NC + 5)
#define NC_   80
#define PLANE (S_ * S_)    // 6400
#define CELLS (NBAT * NA_ * PLANE)   // 307200
#define MAXENT (256 * 15)  // N * 5 offsets * 3 anchors upper bound
#define FLAGW (CELLS / 32) // 9600 words = 38400 B (fits in LDS)
#define OB    300          // obj blocks: 300*256 float4 = CELLS/4 exactly
#define NBLK2 16           // masked/final blocks (ticket count kept tiny: R3 lesson)

__device__ __forceinline__ float sp(float x) {   // softplus, stable
    return fmaxf(x, 0.f) + log1pf(__expf(-fabsf(x)));
}

__device__ __forceinline__ float ciou_f(float x1, float y1, float w1, float h1,
                                        float x2, float y2, float w2, float h2) {
    const float EPS = 1e-7f;
    float b1x1 = x1 - w1 * 0.5f, b1x2 = x1 + w1 * 0.5f;
    float b1y1 = y1 - h1 * 0.5f, b1y2 = y1 + h1 * 0.5f;
    float b2x1 = x2 - w2 * 0.5f, b2x2 = x2 + w2 * 0.5f;
    float b2y1 = y2 - h2 * 0.5f, b2y2 = y2 + h2 * 0.5f;
    float iw = fmaxf(fminf(b1x2, b2x2) - fmaxf(b1x1, b2x1), 0.f);
    float ih = fmaxf(fminf(b1y2, b2y2) - fmaxf(b1y1, b2y1), 0.f);
    float inter = iw * ih;
    float uni = w1 * h1 + w2 * h2 - inter + EPS;
    float iou = inter / uni;
    float cw = fmaxf(b1x2, b2x2) - fminf(b1x1, b2x1);
    float ch = fmaxf(b1y2, b2y2) - fminf(b1y1, b2y1);
    float c2 = cw * cw + ch * ch + EPS;
    float dx = b2x1 + b2x2 - b1x1 - b1x2;
    float dy = b2y1 + b2y2 - b1y1 - b1y2;
    float rho2 = (dx * dx + dy * dy) * 0.25f;
    float da = atanf(w2 / (h2 + EPS)) - atanf(w1 / (h1 + EPS));
    float v = 0.40528473456935109f * da * da;   // 4/pi^2
    float alpha = v / (v - iou + (1.f + EPS));
    return iou - (rho2 / c2 + v * alpha);
}

// ---- node 1: block 0 = LDS-bitmap dedup build (+ zero ticket);
//              blocks 1..OB = dense softplus(pobj) partials (1 float4/thread).
__global__ void __launch_bounds__(256)
k_build_obj(const float* __restrict__ preds,
            const float* __restrict__ tgt, int N,
            int* __restrict__ count, int* __restrict__ done,
            int* __restrict__ lcellcls,     // cell | (cls<<20)
            float4* __restrict__ lbox,
            double* __restrict__ obj_part) {
    if (blockIdx.x == 0) {
        // ---------- build: whole dedup bitmap lives in LDS ----------
        __shared__ unsigned sbm[FLAGW];     // 38400 B
        __shared__ int scount;
        int tid = threadIdx.x;
        for (int i = tid; i < FLAGW; i += 256) sbm[i] = 0u;
        if (tid == 0) { scount = 0; *done = 0; }
        __syncthreads();

        int n = tid;
        if (n < N) {
            int b   = (int)tgt[n * 6 + 0];
            int cls = (int)tgt[n * 6 + 1];
            float bx = tgt[n * 6 + 2], by = tgt[n * 6 + 3];
            float bw = tgt[n * 6 + 4], bh = tgt[n * 6 + 5];
            if (b >= 0 && b < NBAT) {
                const float ax[3] = {12.f / 8.f, 19.f / 8.f, 40.f / 8.f};
                const float ay[3] = {16.f / 8.f, 36.f / 8.f, 28.f / 8.f};
                bool rm[3];
#pragma unroll
                for (int a = 0; a < 3; ++a) {
                    float rx = bw * S_ / ax[a]; rx = fmaxf(rx, 1.f / rx);
                    float ry = bh * S_ / ay[a]; ry = fmaxf(ry, 1.f / ry);
                    rm[a] = fmaxf(rx, ry) < 4.0f;
                }
                float gx = bx * S_, gy = by * S_;
                int ib = (int)floorf(gx), jb = (int)floorf(gy);
                float oi = gx - floorf(gx), oj = gy - floorf(gy);
                bool pos[5];
                pos[0] = true;
                pos[1] = (oi < 0.5f) && (gx > 1.f);
                pos[2] = (oj < 0.5f) && (gy > 1.f);
                pos[3] = (oi > 0.5f) && ((S_ - gx) > 1.f);
                pos[4] = (oj > 0.5f) && ((S_ - gy) > 1.f);
                const int di[5] = {0, -1, 0, 1, 0};
                const int dj[5] = {0, 0, -1, 0, 1};
#pragma unroll
                for (int k = 0; k < 5; ++k) {
                    if (!pos[k]) continue;
                    int ii = ib + di[k], jj = jb + dj[k];
                    if (ii < 0 || ii >= S_ || jj < 0 || jj >= S_) continue; // ref drops OOB
#pragma unroll
                    for (int a = 0; a < 3; ++a) {
                        if (!rm[a]) continue;
                        int cell = ((b * NA_ + a) * S_ + jj) * S_ + ii;
                        unsigned m = 1u << (cell & 31);
                        unsigned old = atomicOr(&sbm[cell >> 5], m);  // LDS atomic
                        if (!(old & m)) {
                            int e = atomicAdd(&scount, 1);            // LDS atomic
                            lcellcls[e] = cell | (cls << 20);
                            lbox[e] = make_float4(bx, by, bw, bh);
                        }
                    }
                }
            }
        }
        __syncthreads();
        if (tid == 0) *count = scount;
    } else {
        // ---------- dense softplus(pobj): 1 float4 per thread ----------
        int tid4 = (blockIdx.x - 1) * 256 + threadIdx.x;   // covers CELLS/4 exactly
        int plane = tid4 / (PLANE / 4);                    // 0..47 (= b*3 + a)
        int pos   = tid4 % (PLANE / 4);
        int a = plane % NA_, b = plane / NA_;
        const float4* p4 = (const float4*)preds;
        float4 q = p4[(size_t)(b * NCH_ + a * 85 + 4) * (PLANE / 4) + pos];
        float v = sp(q.x) + sp(q.y) + sp(q.z) + sp(q.w);
#pragma unroll
        for (int o = 32; o > 0; o >>= 1) v += __shfl_xor(v, o, 64);
        __shared__ float wsum[4];
        int lane = threadIdx.x & 63, wid = threadIdx.x >> 6;
        if (lane == 0) wsum[wid] = v;
        __syncthreads();
        if (threadIdx.x == 0)
            obj_part[blockIdx.x - 1] = (double)(wsum[0] + wsum[1] + wsum[2] + wsum[3]);
    }
}

// ---- node 2: masked gather (grid-stride, 256 waves) + ticket + last-block
//      final reduce. Only NBLK2=16 cross-XCD RMWs total (R3 lesson: keep the
//      contended-atomic count tiny). No spinning -> no deadlock possible.
__global__ void __launch_bounds__(1024)
k_masked_final(const float* __restrict__ preds,
               const int* __restrict__ count,
               const int* __restrict__ lcellcls,
               const float4* __restrict__ lbox,
               const double* __restrict__ obj_part,   // OB entries (from node 1)
               double* __restrict__ partials,         // NBLK2*3
               int* __restrict__ done,
               float* __restrict__ out) {
    int wid = threadIdx.x >> 6, lane = threadIdx.x & 63;
    int gw = blockIdx.x * 16 + wid;                    // 0..255 global wave id
    int cnt = *count;
    double o_a = 0.0, b_a = 0.0, c_a = 0.0;            // valid at lane 0

    for (int t = gw; t < cnt; t += NBLK2 * 16) {
        int packed = lcellcls[t];
        int cell = packed & 0xFFFFF;
        int cls  = packed >> 20;
        int x = cell % S_;
        int y = (cell / S_) % S_;
        int a = (cell / PLANE) % NA_;
        int b = cell / (PLANE * NA_);
        const float* base = preds + (size_t)(b * NCH_ + a * 85) * PLANE + y * S_ + x;
        float v0 = base[lane * PLANE];
        float v1 = (lane < 21) ? base[(64 + lane) * PLANE] : 0.f;
        int clsch = 5 + cls;
        float cs = 0.f;
        if (lane >= 5) { cs += sp(v0); if (lane == clsch) cs -= v0; }
        if (lane < 21) { cs += sp(v1); if (64 + lane == clsch) cs -= v1; }
#pragma unroll
        for (int o = 32; o > 0; o >>= 1) cs += __shfl_xor(cs, o, 64);
        float p0 = __shfl(v0, 0, 64);
        float p1 = __shfl(v0, 1, 64);
        float p2 = __shfl(v0, 2, 64);
        float p3 = __shfl(v0, 3, 64);
        float po = __shfl(v0, 4, 64);

        const float anx[3]  = {12.f, 19.f, 40.f};
        const float any_[3] = {16.f, 36.f, 28.f};
        float sx = 1.f / (1.f + __expf(-p0));
        float sy = 1.f / (1.f + __expf(-p1));
        float px = (sx * 2.f - 0.5f + (float)x) * (1.0f / S_);
        float py = (sy * 2.f - 0.5f + (float)y) * (1.0f / S_);
        float pw = __expf(p2) * anx[a] * (1.0f / 640.f);
        float ph = __expf(p3) * any_[a] * (1.0f / 640.f);

        float4 tb = lbox[t];
        float iou = ciou_f(px, py, pw, ph, tb.x, tb.y, tb.z, tb.w);
        if (lane == 0) {
            b_a += (double)(1.f - iou);
            c_a += (double)cs;
            o_a += (double)(-fmaxf(iou, 0.f) * po);    // bce(x,t) = sp(x) - t*x
        }
    }

    __shared__ double sm[16][3];
    if (lane == 0) { sm[wid][0] = o_a; sm[wid][1] = b_a; sm[wid][2] = c_a; }
    __syncthreads();
    __shared__ int sticket;
    if (threadIdx.x == 0) {
        double o = 0, b = 0, c = 0;
#pragma unroll
        for (int w = 0; w < 16; ++w) { o += sm[w][0]; b += sm[w][1]; c += sm[w][2]; }
        size_t p = (size_t)blockIdx.x * 3;
        __hip_atomic_store(&partials[p + 0], o, __ATOMIC_RELEASE, __HIP_MEMORY_SCOPE_AGENT);
        __hip_atomic_store(&partials[p + 1], b, __ATOMIC_RELEASE, __HIP_MEMORY_SCOPE_AGENT);
        __hip_atomic_store(&partials[p + 2], c, __ATOMIC_RELEASE, __HIP_MEMORY_SCOPE_AGENT);
        sticket = __hip_atomic_fetch_add(done, 1, __ATOMIC_ACQ_REL, __HIP_MEMORY_SCOPE_AGENT);
    }
    __syncthreads();
    if (sticket != NBLK2 - 1) return;

    // ---- last block: deterministic final reduction ----
    int tid = threadIdx.x;
    double o = 0, b = 0, c = 0;
    if (tid < NBLK2) {
        size_t p = (size_t)tid * 3;
        o = __hip_atomic_load(&partials[p + 0], __ATOMIC_ACQUIRE, __HIP_MEMORY_SCOPE_AGENT);
        b = __hip_atomic_load(&partials[p + 1], __ATOMIC_ACQUIRE, __HIP_MEMORY_SCOPE_AGENT);
        c = __hip_atomic_load(&partials[p + 2], __ATOMIC_ACQUIRE, __HIP_MEMORY_SCOPE_AGENT);
    }
    for (int i = tid; i < OB; i += 1024) o += obj_part[i];  // node-1 data: coherent
#pragma unroll
    for (int s = 32; s > 0; s >>= 1) {
        o += __shfl_xor(o, s, 64);
        b += __shfl_xor(b, s, 64);
        c += __shfl_xor(c, s, 64);
    }
    __shared__ double fo[16], fb[16], fc[16];
    if (lane == 0) { fo[wid] = o; fb[wid] = b; fc[wid] = c; }
    __syncthreads();
    if (tid == 0) {
        double so = 0, sb = 0, sc = 0;
#pragma unroll
        for (int w = 0; w < 16; ++w) { so += fo[w]; sb += fb[w]; sc += fc[w]; }
        double nobj  = (double)cnt;
        double denom = fmax(nobj, 1.0);
        double loss_obj = so / (double)CELLS;
        double loss_box = sb / denom;
        double loss_cls = sc / (denom * (double)NC_);
        double loss = (0.7 * 4.0) * loss_obj + 0.3 * loss_cls + 0.05 * loss_box;
        out[0] = (float)(loss * (double)NBAT);
    }
}

extern "C" void kernel_launch(void* const* d_in, const int* in_sizes, int n_in,
                              void* d_out, int out_size, void* d_ws, size_t ws_size,
                              hipStream_t stream) {
    (void)n_in; (void)out_size; (void)ws_size;
    const float* preds = (const float*)d_in[0];
    const float* tgt   = (const float*)d_in[1];
    int N = in_sizes[1] / 6;

    char* ws = (char*)d_ws;
    int*    count    = (int*)(ws + 0);
    int*    done     = (int*)(ws + 8);
    int*    lcellcls = (int*)(ws + 64);                          // MAXENT ints
    float4* lbox     = (float4*)(ws + 64 + MAXENT * 4);          // 15424 % 16 == 0
    double* partials = (double*)(ws + 64 + MAXENT * 4 + MAXENT * 16);  // NBLK2*3
    double* obj_part = partials + (size_t)NBLK2 * 3;             // OB doubles

    k_build_obj<<<1 + OB, 256, 0, stream>>>(preds, tgt, N, count, done,
                                            lcellcls, lbox, obj_part);
    k_masked_final<<<NBLK2, 1024, 0, stream>>>(preds, count, lcellcls, lbox,
                                               obj_part, partials, done, (float*)d_out);
}

// Round 8
// 16.427 us; speedup vs baseline: 1.4640x; 1.4640x over previous
//
#include <hip/hip_runtime.h>
#include <cmath>

// ---------------- problem constants (idx = 0) ----------------
#define S_    80
#define NBAT  16
#define NA_   3
#define NCH_  255          // NB * (NC + 5)
#define NC_   80
#define PLANE (S_ * S_)    // 6400
#define CELLS (NBAT * NA_ * PLANE)   // 307200
#define NMAX  256          // max targets staged in LDS
#define OB    300          // obj blocks: 300*256 float4 = CELLS/4 exactly

__device__ __forceinline__ float sp(float x) {   // softplus, stable
    return fmaxf(x, 0.f) + log1pf(__expf(-fabsf(x)));
}

__device__ __forceinline__ float ciou_f(float x1, float y1, float w1, float h1,
                                        float x2, float y2, float w2, float h2) {
    const float EPS = 1e-7f;
    float b1x1 = x1 - w1 * 0.5f, b1x2 = x1 + w1 * 0.5f;
    float b1y1 = y1 - h1 * 0.5f, b1y2 = y1 + h1 * 0.5f;
    float b2x1 = x2 - w2 * 0.5f, b2x2 = x2 + w2 * 0.5f;
    float b2y1 = y2 - h2 * 0.5f, b2y2 = y2 + h2 * 0.5f;
    float iw = fmaxf(fminf(b1x2, b2x2) - fmaxf(b1x1, b2x1), 0.f);
    float ih = fmaxf(fminf(b1y2, b2y2) - fmaxf(b1y1, b2y1), 0.f);
    float inter = iw * ih;
    float uni = w1 * h1 + w2 * h2 - inter + EPS;
    float iou = inter / uni;
    float cw = fmaxf(b1x2, b2x2) - fminf(b1x1, b2x1);
    float ch = fmaxf(b1y2, b2y2) - fminf(b1y1, b2y1);
    float c2 = cw * cw + ch * ch + EPS;
    float dx = b2x1 + b2x2 - b1x1 - b1x2;
    float dy = b2y1 + b2y2 - b1y1 - b1y2;
    float rho2 = (dx * dx + dy * dy) * 0.25f;
    float da = atanf(w2 / (h2 + EPS)) - atanf(w1 / (h1 + EPS));
    float v = 0.40528473456935109f * da * da;   // 4/pi^2
    float alpha = v / (v - iou + (1.f + EPS));
    return iou - (rho2 / c2 + v * alpha);
}

// ---- node 1 (single kernel, no inter-block state):
//   blocks [0, mblk): one WAVE per raw candidate entry e = bid*4+wid,
//     e -> (n = e/15, k = (e%15)/3, a = e%3). The wave validates its entry,
//     then runs a CANONICAL-OWNERSHIP test: abstain iff some earlier target
//     n' < n (same image) also maps to this cell. Winning set == dedup set,
//     computed independently by every wave -> no build pass, no atomics.
//   blocks [mblk, mblk+OB): dense softplus(pobj) partials (1 float4/thread).
__global__ void __launch_bounds__(256)
k_main(const float* __restrict__ preds,
       const float* __restrict__ tgt, int N, int mblk,
       double* __restrict__ partials) {   // 4 doubles per block: o, box, cls, cnt
    int bid = blockIdx.x;
    int lane = threadIdx.x & 63, wid = threadIdx.x >> 6;
    double o_p = 0.0, b_p = 0.0, c_p = 0.0, n_p = 0.0;
    __shared__ double sm[4][4];

    if (bid < mblk) {
        // -------- stage target table in LDS (6 KB), wave-uniform reuse ------
        __shared__ float st[NMAX * 6];
        int tot = N * 6;
        for (int i = threadIdx.x; i < tot; i += 256) st[i] = tgt[i];
        __syncthreads();

        const float ax[3] = {12.f / 8.f, 19.f / 8.f, 40.f / 8.f};
        const float ay[3] = {16.f / 8.f, 36.f / 8.f, 28.f / 8.f};
        const int di[5] = {0, -1, 0, 1, 0};
        const int dj[5] = {0, 0, -1, 0, 1};

        int e = bid * 4 + wid;
        int n = e / 15, r = e % 15, k = r / 3, a = r % 3;
        bool valid = (n < N);
        int b = 0, cls = 0, ii = 0, jj = 0;
        float bx = 0.f, by = 0.f, bw = 0.f, bh = 0.f;
        if (valid) {
            b   = (int)st[n * 6 + 0];
            cls = (int)st[n * 6 + 1];
            bx = st[n * 6 + 2]; by = st[n * 6 + 3];
            bw = st[n * 6 + 4]; bh = st[n * 6 + 5];
            valid = (b >= 0 && b < NBAT);
        }
        if (valid) {
            float rx = bw * S_ / ax[a]; rx = fmaxf(rx, 1.f / rx);
            float ry = bh * S_ / ay[a]; ry = fmaxf(ry, 1.f / ry);
            bool rm = fmaxf(rx, ry) < 4.0f;
            float gx = bx * S_, gy = by * S_;
            int ib = (int)floorf(gx), jb = (int)floorf(gy);
            float oi = gx - floorf(gx), oj = gy - floorf(gy);
            bool pos;
            switch (k) {
                case 0: pos = true; break;
                case 1: pos = (oi < 0.5f) && (gx > 1.f); break;
                case 2: pos = (oj < 0.5f) && (gy > 1.f); break;
                case 3: pos = (oi > 0.5f) && ((S_ - gx) > 1.f); break;
                default: pos = (oj > 0.5f) && ((S_ - gy) > 1.f); break;
            }
            ii = ib + di[k]; jj = jb + dj[k];
            valid = rm && pos && ii >= 0 && ii < S_ && jj >= 0 && jj < S_; // ref drops OOB
        }

        // -------- canonical-ownership: any earlier target hit this cell? ----
        bool conflict = false;
        if (valid) {
#pragma unroll
            for (int l4 = 0; l4 < 4; ++l4) {
                int m = lane + l4 * 64;                 // candidate earlier target
                if (m < n) {                            // (m < n <= N)
                    int b2 = (int)st[m * 6 + 0];
                    if (b2 == b) {
                        float bw2 = st[m * 6 + 4], bh2 = st[m * 6 + 5];
                        float rx2 = bw2 * S_ / ax[a]; rx2 = fmaxf(rx2, 1.f / rx2);
                        float ry2 = bh2 * S_ / ay[a]; ry2 = fmaxf(ry2, 1.f / ry2);
                        if (fmaxf(rx2, ry2) < 4.0f) {
                            float gx2 = st[m * 6 + 2] * S_, gy2 = st[m * 6 + 3] * S_;
                            int ib2 = (int)floorf(gx2), jb2 = (int)floorf(gy2);
                            float oi2 = gx2 - floorf(gx2), oj2 = gy2 - floorf(gy2);
                            bool pos2[5];
                            pos2[0] = true;
                            pos2[1] = (oi2 < 0.5f) && (gx2 > 1.f);
                            pos2[2] = (oj2 < 0.5f) && (gy2 > 1.f);
                            pos2[3] = (oi2 > 0.5f) && ((S_ - gx2) > 1.f);
                            pos2[4] = (oj2 > 0.5f) && ((S_ - gy2) > 1.f);
#pragma unroll
                            for (int k2 = 0; k2 < 5; ++k2)
                                if (pos2[k2] && (ib2 + di[k2] == ii) && (jb2 + dj[k2] == jj))
                                    conflict = true;
                        }
                    }
                }
            }
        }
        bool win = valid && (__ballot(conflict) == 0ull);

        // -------- winner gathers 85 channels and computes losses ------------
        double obj_c = 0.0, box_t = 0.0, cls_s = 0.0;
        if (win) {
            int x = ii, y = jj;
            const float* base = preds + (size_t)(b * NCH_ + a * 85) * PLANE + y * S_ + x;
            float v0 = base[lane * PLANE];
            float v1 = (lane < 21) ? base[(64 + lane) * PLANE] : 0.f;
            int clsch = 5 + cls;
            float cs = 0.f;
            if (lane >= 5) { cs += sp(v0); if (lane == clsch) cs -= v0; }
            if (lane < 21) { cs += sp(v1); if (64 + lane == clsch) cs -= v1; }
#pragma unroll
            for (int o = 32; o > 0; o >>= 1) cs += __shfl_xor(cs, o, 64);
            float p0 = __shfl(v0, 0, 64);
            float p1 = __shfl(v0, 1, 64);
            float p2 = __shfl(v0, 2, 64);
            float p3 = __shfl(v0, 3, 64);
            float po = __shfl(v0, 4, 64);

            const float anx[3]  = {12.f, 19.f, 40.f};
            const float any_[3] = {16.f, 36.f, 28.f};
            float sx = 1.f / (1.f + __expf(-p0));
            float sy = 1.f / (1.f + __expf(-p1));
            float px = (sx * 2.f - 0.5f + (float)x) * (1.0f / S_);
            float py = (sy * 2.f - 0.5f + (float)y) * (1.0f / S_);
            float pw = __expf(p2) * anx[a] * (1.0f / 640.f);
            float ph = __expf(p3) * any_[a] * (1.0f / 640.f);

            float iou = ciou_f(px, py, pw, ph, bx, by, bw, bh);
            if (lane == 0) {
                box_t = (double)(1.f - iou);
                cls_s = (double)cs;
                obj_c = (double)(-fmaxf(iou, 0.f) * po);   // bce(x,t) = sp(x) - t*x
            }
        }
        if (lane == 0) {
            sm[wid][0] = obj_c; sm[wid][1] = box_t; sm[wid][2] = cls_s;
            sm[wid][3] = win ? 1.0 : 0.0;
        }
        __syncthreads();
        if (threadIdx.x == 0) {
#pragma unroll
            for (int w = 0; w < 4; ++w) {
                o_p += sm[w][0]; b_p += sm[w][1]; c_p += sm[w][2]; n_p += sm[w][3];
            }
        }
    } else {
        // -------- dense softplus(pobj): 1 float4 per thread -----------------
        int tid4 = (bid - mblk) * 256 + threadIdx.x;   // covers CELLS/4 exactly
        int plane = tid4 / (PLANE / 4);                // 0..47 (= b*3 + a)
        int pos   = tid4 % (PLANE / 4);
        int a = plane % NA_, b = plane / NA_;
        const float4* p4 = (const float4*)preds;
        float4 q = p4[(size_t)(b * NCH_ + a * 85 + 4) * (PLANE / 4) + pos];
        float v = sp(q.x) + sp(q.y) + sp(q.z) + sp(q.w);
#pragma unroll
        for (int o = 32; o > 0; o >>= 1) v += __shfl_xor(v, o, 64);
        if (lane == 0) { sm[wid][0] = (double)v; }
        __syncthreads();
        if (threadIdx.x == 0) {
#pragma unroll
            for (int w = 0; w < 4; ++w) o_p += sm[w][0];
        }
    }

    if (threadIdx.x == 0) {
        double* p = partials + (size_t)bid * 4;
        p[0] = o_p; p[1] = b_p; p[2] = c_p; p[3] = n_p;  // every slot written every call
    }
}

// ---- node 2: deterministic final reduce + scalar ----
__global__ void __launch_bounds__(1024)
k_final(const double* __restrict__ partials, int totblk,
        float* __restrict__ out) {
    int tid = threadIdx.x;
    int lane = tid & 63, wid = tid >> 6;
    double o = 0, b = 0, c = 0, n = 0;
    for (int i = tid; i < totblk; i += 1024) {
        const double* p = partials + (size_t)i * 4;
        o += p[0]; b += p[1]; c += p[2]; n += p[3];
    }
#pragma unroll
    for (int s = 32; s > 0; s >>= 1) {
        o += __shfl_xor(o, s, 64);
        b += __shfl_xor(b, s, 64);
        c += __shfl_xor(c, s, 64);
        n += __shfl_xor(n, s, 64);
    }
    __shared__ double fo[16], fb[16], fc[16], fn[16];
    if (lane == 0) { fo[wid] = o; fb[wid] = b; fc[wid] = c; fn[wid] = n; }
    __syncthreads();
    if (tid == 0) {
        double so = 0, sb = 0, sc = 0, sn = 0;
#pragma unroll
        for (int w = 0; w < 16; ++w) { so += fo[w]; sb += fb[w]; sc += fc[w]; sn += fn[w]; }
        double denom = fmax(sn, 1.0);
        double loss_obj = so / (double)CELLS;
        double loss_box = sb / denom;
        double loss_cls = sc / (denom * (double)NC_);
        double loss = (0.7 * 4.0) * loss_obj + 0.3 * loss_cls + 0.05 * loss_box;
        out[0] = (float)(loss * (double)NBAT);
    }
}

extern "C" void kernel_launch(void* const* d_in, const int* in_sizes, int n_in,
                              void* d_out, int out_size, void* d_ws, size_t ws_size,
                              hipStream_t stream) {
    (void)n_in; (void)out_size; (void)ws_size;
    const float* preds = (const float*)d_in[0];
    const float* tgt   = (const float*)d_in[1];
    int N = in_sizes[1] / 6;
    if (N > NMAX) N = NMAX;   // LDS staging capacity (setup uses N=256)

    double* partials = (double*)d_ws;          // (mblk+OB)*4 doubles
    int mblk   = (N * 15 + 3) / 4;             // 960 for N=256
    int totblk = mblk + OB;                    // 1260

    k_main<<<totblk, 256, 0, stream>>>(preds, tgt, N, mblk, partials);
    k_final<<<1, 1024, 0, stream>>>(partials, totblk, (float*)d_out);
}

// Round 9
// 15.115 us; speedup vs baseline: 1.5910x; 1.0868x over previous
//
#include <hip/hip_runtime.h>
#include <cmath>

// ---------------- problem constants (idx = 0) ----------------
#define S_    80
#define NBAT  16
#define NA_   3
#define NCH_  255          // NB * (NC + 5)
#define NC_   80
#define PLANE (S_ * S_)    // 6400
#define CELLS (NBAT * NA_ * PLANE)   // 307200
#define NMAX  256          // max targets staged in LDS
#define WPB   8            // waves per block (512 threads)
#define MB    (NMAX * 15 / WPB)      // 480 masked blocks (3840 candidate waves)
#define OBB   (CELLS / 4 / 512)      // 150 obj blocks, 1 float4/thread

__device__ __forceinline__ float sp(float x) {   // softplus, stable
    return fmaxf(x, 0.f) + log1pf(__expf(-fabsf(x)));
}

__device__ __forceinline__ float ciou_f(float x1, float y1, float w1, float h1,
                                        float x2, float y2, float w2, float h2) {
    const float EPS = 1e-7f;
    float b1x1 = x1 - w1 * 0.5f, b1x2 = x1 + w1 * 0.5f;
    float b1y1 = y1 - h1 * 0.5f, b1y2 = y1 + h1 * 0.5f;
    float b2x1 = x2 - w2 * 0.5f, b2x2 = x2 + w2 * 0.5f;
    float b2y1 = y2 - h2 * 0.5f, b2y2 = y2 + h2 * 0.5f;
    float iw = fmaxf(fminf(b1x2, b2x2) - fmaxf(b1x1, b2x1), 0.f);
    float ih = fmaxf(fminf(b1y2, b2y2) - fmaxf(b1y1, b2y1), 0.f);
    float inter = iw * ih;
    float uni = w1 * h1 + w2 * h2 - inter + EPS;
    float iou = inter / uni;
    float cw = fmaxf(b1x2, b2x2) - fminf(b1x1, b2x1);
    float ch = fmaxf(b1y2, b2y2) - fminf(b1y1, b2y1);
    float c2 = cw * cw + ch * ch + EPS;
    float dx = b2x1 + b2x2 - b1x1 - b1x2;
    float dy = b2y1 + b2y2 - b1y1 - b1y2;
    float rho2 = (dx * dx + dy * dy) * 0.25f;
    float da = atanf(w2 / (h2 + EPS)) - atanf(w1 / (h1 + EPS));
    float v = 0.40528473456935109f * da * da;   // 4/pi^2
    float alpha = v / (v - iou + (1.f + EPS));
    return iou - (rho2 / c2 + v * alpha);
}

// ---- node 1 (single kernel, no inter-block state):
//   blocks [0, mblk): 8 waves/block, one WAVE per raw candidate entry
//     e = bid*8 + wid -> (n = e/15, k = (e%15)/3, a = e%3). Wave validates,
//     then canonical-ownership test (abstain iff an earlier target n' < n in
//     the same image maps to the same cell) -> dedup with no atomics.
//   blocks [mblk, mblk+OBB): dense softplus(pobj) partials (1 float4/thread).
__global__ void __launch_bounds__(512)
k_main(const float* __restrict__ preds,
       const float* __restrict__ tgt, int N, int mblk,
       double* __restrict__ partials) {   // 4 doubles per block: o, box, cls, cnt
    int bid = blockIdx.x;
    int lane = threadIdx.x & 63, wid = threadIdx.x >> 6;
    double o_p = 0.0, b_p = 0.0, c_p = 0.0, n_p = 0.0;
    __shared__ double sm[WPB][4];

    if (bid < mblk) {
        // -------- stage target table in LDS (6 KB), shared by 8 waves ------
        __shared__ float st[NMAX * 6];
        int tot = N * 6;
        for (int i = threadIdx.x; i < tot; i += 512) st[i] = tgt[i];
        __syncthreads();

        const float ax[3] = {12.f / 8.f, 19.f / 8.f, 40.f / 8.f};
        const float ay[3] = {16.f / 8.f, 36.f / 8.f, 28.f / 8.f};
        const int di[5] = {0, -1, 0, 1, 0};
        const int dj[5] = {0, 0, -1, 0, 1};

        int e = bid * WPB + wid;
        int n = e / 15, r = e % 15, k = r / 3, a = r % 3;
        bool valid = (n < N);
        int b = 0, cls = 0, ii = 0, jj = 0;
        float bx = 0.f, by = 0.f, bw = 0.f, bh = 0.f;
        if (valid) {
            b   = (int)st[n * 6 + 0];
            cls = (int)st[n * 6 + 1];
            bx = st[n * 6 + 2]; by = st[n * 6 + 3];
            bw = st[n * 6 + 4]; bh = st[n * 6 + 5];
            valid = (b >= 0 && b < NBAT);
        }
        if (valid) {
            float rx = bw * S_ / ax[a]; rx = fmaxf(rx, 1.f / rx);
            float ry = bh * S_ / ay[a]; ry = fmaxf(ry, 1.f / ry);
            bool rm = fmaxf(rx, ry) < 4.0f;
            float gx = bx * S_, gy = by * S_;
            int ib = (int)floorf(gx), jb = (int)floorf(gy);
            float oi = gx - floorf(gx), oj = gy - floorf(gy);
            bool pos;
            switch (k) {
                case 0: pos = true; break;
                case 1: pos = (oi < 0.5f) && (gx > 1.f); break;
                case 2: pos = (oj < 0.5f) && (gy > 1.f); break;
                case 3: pos = (oi > 0.5f) && ((S_ - gx) > 1.f); break;
                default: pos = (oj > 0.5f) && ((S_ - gy) > 1.f); break;
            }
            ii = ib + di[k]; jj = jb + dj[k];
            valid = rm && pos && ii >= 0 && ii < S_ && jj >= 0 && jj < S_; // ref drops OOB
        }

        // -------- canonical-ownership: any earlier target hit this cell? ----
        bool conflict = false;
        if (valid) {
#pragma unroll
            for (int l4 = 0; l4 < 4; ++l4) {
                int m = lane + l4 * 64;                 // candidate earlier target
                if (m < n) {                            // (m < n <= N)
                    int b2 = (int)st[m * 6 + 0];
                    if (b2 == b) {
                        float bw2 = st[m * 6 + 4], bh2 = st[m * 6 + 5];
                        float rx2 = bw2 * S_ / ax[a]; rx2 = fmaxf(rx2, 1.f / rx2);
                        float ry2 = bh2 * S_ / ay[a]; ry2 = fmaxf(ry2, 1.f / ry2);
                        if (fmaxf(rx2, ry2) < 4.0f) {
                            float gx2 = st[m * 6 + 2] * S_, gy2 = st[m * 6 + 3] * S_;
                            int ib2 = (int)floorf(gx2), jb2 = (int)floorf(gy2);
                            float oi2 = gx2 - floorf(gx2), oj2 = gy2 - floorf(gy2);
                            bool pos2[5];
                            pos2[0] = true;
                            pos2[1] = (oi2 < 0.5f) && (gx2 > 1.f);
                            pos2[2] = (oj2 < 0.5f) && (gy2 > 1.f);
                            pos2[3] = (oi2 > 0.5f) && ((S_ - gx2) > 1.f);
                            pos2[4] = (oj2 > 0.5f) && ((S_ - gy2) > 1.f);
#pragma unroll
                            for (int k2 = 0; k2 < 5; ++k2)
                                if (pos2[k2] && (ib2 + di[k2] == ii) && (jb2 + dj[k2] == jj))
                                    conflict = true;
                        }
                    }
                }
            }
        }
        bool win = valid && (__ballot(conflict) == 0ull);

        // -------- winner gathers 85 channels and computes losses ------------
        double obj_c = 0.0, box_t = 0.0, cls_s = 0.0;
        if (win) {
            int x = ii, y = jj;
            const float* base = preds + (size_t)(b * NCH_ + a * 85) * PLANE + y * S_ + x;
            float v0 = base[lane * PLANE];
            float v1 = (lane < 21) ? base[(64 + lane) * PLANE] : 0.f;
            int clsch = 5 + cls;
            float cs = 0.f;
            if (lane >= 5) { cs += sp(v0); if (lane == clsch) cs -= v0; }
            if (lane < 21) { cs += sp(v1); if (64 + lane == clsch) cs -= v1; }
#pragma unroll
            for (int o = 32; o > 0; o >>= 1) cs += __shfl_xor(cs, o, 64);
            float p0 = __shfl(v0, 0, 64);
            float p1 = __shfl(v0, 1, 64);
            float p2 = __shfl(v0, 2, 64);
            float p3 = __shfl(v0, 3, 64);
            float po = __shfl(v0, 4, 64);

            const float anx[3]  = {12.f, 19.f, 40.f};
            const float any_[3] = {16.f, 36.f, 28.f};
            float sx = 1.f / (1.f + __expf(-p0));
            float sy = 1.f / (1.f + __expf(-p1));
            float px = (sx * 2.f - 0.5f + (float)x) * (1.0f / S_);
            float py = (sy * 2.f - 0.5f + (float)y) * (1.0f / S_);
            float pw = __expf(p2) * anx[a] * (1.0f / 640.f);
            float ph = __expf(p3) * any_[a] * (1.0f / 640.f);

            float iou = ciou_f(px, py, pw, ph, bx, by, bw, bh);
            if (lane == 0) {
                box_t = (double)(1.f - iou);
                cls_s = (double)cs;
                obj_c = (double)(-fmaxf(iou, 0.f) * po);   // bce(x,t) = sp(x) - t*x
            }
        }
        if (lane == 0) {
            sm[wid][0] = obj_c; sm[wid][1] = box_t; sm[wid][2] = cls_s;
            sm[wid][3] = win ? 1.0 : 0.0;
        }
        __syncthreads();
        if (threadIdx.x == 0) {
#pragma unroll
            for (int w = 0; w < WPB; ++w) {
                o_p += sm[w][0]; b_p += sm[w][1]; c_p += sm[w][2]; n_p += sm[w][3];
            }
        }
    } else {
        // -------- dense softplus(pobj): 1 float4 per thread -----------------
        int tid4 = (bid - mblk) * 512 + threadIdx.x;   // covers CELLS/4 exactly
        int plane = tid4 / (PLANE / 4);                // 0..47 (= b*3 + a)
        int pos   = tid4 % (PLANE / 4);
        int a = plane % NA_, b = plane / NA_;
        const float4* p4 = (const float4*)preds;
        float4 q = p4[(size_t)(b * NCH_ + a * 85 + 4) * (PLANE / 4) + pos];
        float v = sp(q.x) + sp(q.y) + sp(q.z) + sp(q.w);
#pragma unroll
        for (int o = 32; o > 0; o >>= 1) v += __shfl_xor(v, o, 64);
        if (lane == 0) { sm[wid][0] = (double)v; }
        __syncthreads();
        if (threadIdx.x == 0) {
#pragma unroll
            for (int w = 0; w < WPB; ++w) o_p += sm[w][0];
        }
    }

    if (threadIdx.x == 0) {
        double* p = partials + (size_t)bid * 4;
        p[0] = o_p; p[1] = b_p; p[2] = c_p; p[3] = n_p;  // every slot written every call
    }
}

// ---- node 2: deterministic final reduce + scalar ----
__global__ void __launch_bounds__(512)
k_final(const double* __restrict__ partials, int totblk,
        float* __restrict__ out) {
    int tid = threadIdx.x;
    int lane = tid & 63, wid = tid >> 6;
    double o = 0, b = 0, c = 0, n = 0;
    for (int i = tid; i < totblk; i += 512) {
        const double* p = partials + (size_t)i * 4;
        o += p[0]; b += p[1]; c += p[2]; n += p[3];
    }
#pragma unroll
    for (int s = 32; s > 0; s >>= 1) {
        o += __shfl_xor(o, s, 64);
        b += __shfl_xor(b, s, 64);
        c += __shfl_xor(c, s, 64);
        n += __shfl_xor(n, s, 64);
    }
    __shared__ double fo[8], fb[8], fc[8], fn[8];
    if (lane == 0) { fo[wid] = o; fb[wid] = b; fc[wid] = c; fn[wid] = n; }
    __syncthreads();
    if (tid == 0) {
        double so = 0, sb = 0, sc = 0, sn = 0;
#pragma unroll
        for (int w = 0; w < 8; ++w) { so += fo[w]; sb += fb[w]; sc += fc[w]; sn += fn[w]; }
        double denom = fmax(sn, 1.0);
        double loss_obj = so / (double)CELLS;
        double loss_box = sb / denom;
        double loss_cls = sc / (denom * (double)NC_);
        double loss = (0.7 * 4.0) * loss_obj + 0.3 * loss_cls + 0.05 * loss_box;
        out[0] = (float)(loss * (double)NBAT);
    }
}

extern "C" void kernel_launch(void* const* d_in, const int* in_sizes, int n_in,
                              void* d_out, int out_size, void* d_ws, size_t ws_size,
                              hipStream_t stream) {
    (void)n_in; (void)out_size; (void)ws_size;
    const float* preds = (const float*)d_in[0];
    const float* tgt   = (const float*)d_in[1];
    int N = in_sizes[1] / 6;
    if (N > NMAX) N = NMAX;   // LDS staging capacity (setup uses N=256)

    double* partials = (double*)d_ws;            // (mblk+OBB)*4 doubles
    int mblk   = (N * 15 + WPB - 1) / WPB;       // 480 for N=256
    int totblk = mblk + OBB;                     // 630

    k_main<<<totblk, 512, 0, stream>>>(preds, tgt, N, mblk, partials);
    k_final<<<1, 512, 0, stream>>>(partials, totblk, (float*)d_out);
}

// Round 10
// 14.367 us; speedup vs baseline: 1.6738x; 1.0520x over previous
//
#include <hip/hip_runtime.h>
#include <cmath>

// ---------------- problem constants (idx = 0) ----------------
#define S_    80
#define NBAT  16
#define NA_   3
#define NCH_  255          // NB * (NC + 5)
#define NC_   80
#define PLANE (S_ * S_)    // 6400
#define CELLS (NBAT * NA_ * PLANE)   // 307200
#define NMAX  256          // max targets
#define WPB   8            // waves per block (512 threads)
#define OBB   (CELLS / 4 / 512 / 2)  // 75 obj blocks, 2 float4/thread

__device__ __forceinline__ float sp(float x) {   // softplus, stable
    return fmaxf(x, 0.f) + log1pf(__expf(-fabsf(x)));
}

__device__ __forceinline__ float ciou_f(float x1, float y1, float w1, float h1,
                                        float x2, float y2, float w2, float h2) {
    const float EPS = 1e-7f;
    float b1x1 = x1 - w1 * 0.5f, b1x2 = x1 + w1 * 0.5f;
    float b1y1 = y1 - h1 * 0.5f, b1y2 = y1 + h1 * 0.5f;
    float b2x1 = x2 - w2 * 0.5f, b2x2 = x2 + w2 * 0.5f;
    float b2y1 = y2 - h2 * 0.5f, b2y2 = y2 + h2 * 0.5f;
    float iw = fmaxf(fminf(b1x2, b2x2) - fmaxf(b1x1, b2x1), 0.f);
    float ih = fmaxf(fminf(b1y2, b2y2) - fmaxf(b1y1, b2y1), 0.f);
    float inter = iw * ih;
    float uni = w1 * h1 + w2 * h2 - inter + EPS;
    float iou = inter / uni;
    float cw = fmaxf(b1x2, b2x2) - fminf(b1x1, b2x1);
    float ch = fmaxf(b1y2, b2y2) - fminf(b1y1, b2y1);
    float c2 = cw * cw + ch * ch + EPS;
    float dx = b2x1 + b2x2 - b1x1 - b1x2;
    float dy = b2y1 + b2y2 - b1y1 - b1y2;
    float rho2 = (dx * dx + dy * dy) * 0.25f;
    float da = atanf(w2 / (h2 + EPS)) - atanf(w1 / (h1 + EPS));
    float v = 0.40528473456935109f * da * da;   // 4/pi^2
    float alpha = v / (v - iou + (1.f + EPS));
    return iou - (rho2 / c2 + v * alpha);
}

// ---- node 1 (single kernel, no inter-block state, no LDS staging):
//   blocks [0, mblk): 8 waves/block, one WAVE per raw candidate entry
//     e = bid*8 + wid -> (n = e/15, k = (e%15)/3, a = e%3). Wave validates,
//     then canonical-ownership test (abstain iff an earlier target n' < n in
//     the same image maps to the same cell) -> dedup with no atomics.
//     tgt is read directly (6 KB table, L1/L2-resident after first touch).
//   blocks [mblk, mblk+OBB): dense softplus(pobj) partials (2 float4/thread).
__global__ void __launch_bounds__(512)
k_main(const float* __restrict__ preds,
       const float* __restrict__ tgt, int N, int mblk,
       float4* __restrict__ partials) {   // per block: {obj, box, cls, cnt}
    int bid = blockIdx.x;
    int lane = threadIdx.x & 63, wid = threadIdx.x >> 6;
    float o_p = 0.f, b_p = 0.f, c_p = 0.f, n_p = 0.f;
    __shared__ float smf[WPB][4];

    if (bid < mblk) {
        const float ax[3] = {12.f / 8.f, 19.f / 8.f, 40.f / 8.f};
        const float ay[3] = {16.f / 8.f, 36.f / 8.f, 28.f / 8.f};
        const int di[5] = {0, -1, 0, 1, 0};
        const int dj[5] = {0, 0, -1, 0, 1};

        int e = bid * WPB + wid;
        int n = e / 15, r = e % 15, k = r / 3, a = r % 3;
        bool valid = (n < N);
        int b = 0, cls = 0, ii = 0, jj = 0;
        float bx = 0.f, by = 0.f, bw = 0.f, bh = 0.f;
        if (valid) {
            b   = (int)tgt[n * 6 + 0];
            cls = (int)tgt[n * 6 + 1];
            bx = tgt[n * 6 + 2]; by = tgt[n * 6 + 3];
            bw = tgt[n * 6 + 4]; bh = tgt[n * 6 + 5];
            valid = (b >= 0 && b < NBAT);
        }
        if (valid) {
            float rx = bw * S_ / ax[a]; rx = fmaxf(rx, 1.f / rx);
            float ry = bh * S_ / ay[a]; ry = fmaxf(ry, 1.f / ry);
            bool rm = fmaxf(rx, ry) < 4.0f;
            float gx = bx * S_, gy = by * S_;
            int ib = (int)floorf(gx), jb = (int)floorf(gy);
            float oi = gx - floorf(gx), oj = gy - floorf(gy);
            bool pos;
            switch (k) {
                case 0: pos = true; break;
                case 1: pos = (oi < 0.5f) && (gx > 1.f); break;
                case 2: pos = (oj < 0.5f) && (gy > 1.f); break;
                case 3: pos = (oi > 0.5f) && ((S_ - gx) > 1.f); break;
                default: pos = (oj > 0.5f) && ((S_ - gy) > 1.f); break;
            }
            ii = ib + di[k]; jj = jb + dj[k];
            valid = rm && pos && ii >= 0 && ii < S_ && jj >= 0 && jj < S_; // ref drops OOB
        }

        // -------- canonical-ownership: any earlier target hit this cell? ----
        bool conflict = false;
        if (valid) {
#pragma unroll
            for (int l4 = 0; l4 < 4; ++l4) {
                int m = lane + l4 * 64;                 // candidate earlier target
                if (m < n) {                            // (m < n <= N)
                    int b2 = (int)tgt[m * 6 + 0];
                    if (b2 == b) {
                        float bw2 = tgt[m * 6 + 4], bh2 = tgt[m * 6 + 5];
                        float rx2 = bw2 * S_ / ax[a]; rx2 = fmaxf(rx2, 1.f / rx2);
                        float ry2 = bh2 * S_ / ay[a]; ry2 = fmaxf(ry2, 1.f / ry2);
                        if (fmaxf(rx2, ry2) < 4.0f) {
                            float gx2 = tgt[m * 6 + 2] * S_, gy2 = tgt[m * 6 + 3] * S_;
                            int ib2 = (int)floorf(gx2), jb2 = (int)floorf(gy2);
                            float oi2 = gx2 - floorf(gx2), oj2 = gy2 - floorf(gy2);
                            bool pos2[5];
                            pos2[0] = true;
                            pos2[1] = (oi2 < 0.5f) && (gx2 > 1.f);
                            pos2[2] = (oj2 < 0.5f) && (gy2 > 1.f);
                            pos2[3] = (oi2 > 0.5f) && ((S_ - gx2) > 1.f);
                            pos2[4] = (oj2 > 0.5f) && ((S_ - gy2) > 1.f);
#pragma unroll
                            for (int k2 = 0; k2 < 5; ++k2)
                                if (pos2[k2] && (ib2 + di[k2] == ii) && (jb2 + dj[k2] == jj))
                                    conflict = true;
                        }
                    }
                }
            }
        }
        bool win = valid && (__ballot(conflict) == 0ull);

        // -------- winner gathers 85 channels and computes losses ------------
        float obj_c = 0.f, box_t = 0.f, cls_s = 0.f;
        if (win) {
            int x = ii, y = jj;
            const float* base = preds + (size_t)(b * NCH_ + a * 85) * PLANE + y * S_ + x;
            float v0 = base[lane * PLANE];
            float v1 = (lane < 21) ? base[(64 + lane) * PLANE] : 0.f;
            int clsch = 5 + cls;
            float cs = 0.f;
            if (lane >= 5) { cs += sp(v0); if (lane == clsch) cs -= v0; }
            if (lane < 21) { cs += sp(v1); if (64 + lane == clsch) cs -= v1; }
#pragma unroll
            for (int o = 32; o > 0; o >>= 1) cs += __shfl_xor(cs, o, 64);
            float p0 = __shfl(v0, 0, 64);
            float p1 = __shfl(v0, 1, 64);
            float p2 = __shfl(v0, 2, 64);
            float p3 = __shfl(v0, 3, 64);
            float po = __shfl(v0, 4, 64);

            const float anx[3]  = {12.f, 19.f, 40.f};
            const float any_[3] = {16.f, 36.f, 28.f};
            float sx = 1.f / (1.f + __expf(-p0));
            float sy = 1.f / (1.f + __expf(-p1));
            float px = (sx * 2.f - 0.5f + (float)x) * (1.0f / S_);
            float py = (sy * 2.f - 0.5f + (float)y) * (1.0f / S_);
            float pw = __expf(p2) * anx[a] * (1.0f / 640.f);
            float ph = __expf(p3) * any_[a] * (1.0f / 640.f);

            float iou = ciou_f(px, py, pw, ph, bx, by, bw, bh);
            if (lane == 0) {
                box_t = 1.f - iou;
                cls_s = cs;
                obj_c = -fmaxf(iou, 0.f) * po;   // bce(x,t) = sp(x) - t*x
            }
        }
        if (lane == 0) {
            smf[wid][0] = obj_c; smf[wid][1] = box_t; smf[wid][2] = cls_s;
            smf[wid][3] = win ? 1.f : 0.f;
        }
        __syncthreads();
        if (threadIdx.x == 0) {
#pragma unroll
            for (int w = 0; w < WPB; ++w) {
                o_p += smf[w][0]; b_p += smf[w][1]; c_p += smf[w][2]; n_p += smf[w][3];
            }
        }
    } else {
        // -------- dense softplus(pobj): 2 float4 per thread -----------------
        const float4* p4 = (const float4*)preds;
        float v = 0.f;
#pragma unroll
        for (int rr = 0; rr < 2; ++rr) {
            int tid4 = (bid - mblk) * 1024 + rr * 512 + threadIdx.x;  // CELLS/4 exact
            int plane = tid4 / (PLANE / 4);                // 0..47 (= b*3 + a)
            int pos   = tid4 % (PLANE / 4);
            int a = plane % NA_, b = plane / NA_;
            float4 q = p4[(size_t)(b * NCH_ + a * 85 + 4) * (PLANE / 4) + pos];
            v += sp(q.x) + sp(q.y) + sp(q.z) + sp(q.w);
        }
#pragma unroll
        for (int o = 32; o > 0; o >>= 1) v += __shfl_xor(v, o, 64);
        if (lane == 0) { smf[wid][0] = v; }
        __syncthreads();
        if (threadIdx.x == 0) {
#pragma unroll
            for (int w = 0; w < WPB; ++w) o_p += smf[w][0];
        }
    }

    if (threadIdx.x == 0)
        partials[bid] = make_float4(o_p, b_p, c_p, n_p);  // written every call
}

// ---- node 2: deterministic final reduce (double accum) + scalar ----
__global__ void __launch_bounds__(256)
k_final(const float4* __restrict__ partials, int totblk,
        float* __restrict__ out) {
    int tid = threadIdx.x;
    int lane = tid & 63, wid = tid >> 6;
    double o = 0, b = 0, c = 0, n = 0;
    for (int i = tid; i < totblk; i += 256) {
        float4 p = partials[i];
        o += (double)p.x; b += (double)p.y; c += (double)p.z; n += (double)p.w;
    }
#pragma unroll
    for (int s = 32; s > 0; s >>= 1) {
        o += __shfl_xor(o, s, 64);
        b += __shfl_xor(b, s, 64);
        c += __shfl_xor(c, s, 64);
        n += __shfl_xor(n, s, 64);
    }
    __shared__ double fo[4], fb[4], fc[4], fn[4];
    if (lane == 0) { fo[wid] = o; fb[wid] = b; fc[wid] = c; fn[wid] = n; }
    __syncthreads();
    if (tid == 0) {
        double so = 0, sb = 0, sc = 0, sn = 0;
#pragma unroll
        for (int w = 0; w < 4; ++w) { so += fo[w]; sb += fb[w]; sc += fc[w]; sn += fn[w]; }
        double denom = fmax(sn, 1.0);
        double loss_obj = so / (double)CELLS;
        double loss_box = sb / denom;
        double loss_cls = sc / (denom * (double)NC_);
        double loss = (0.7 * 4.0) * loss_obj + 0.3 * loss_cls + 0.05 * loss_box;
        out[0] = (float)(loss * (double)NBAT);
    }
}

extern "C" void kernel_launch(void* const* d_in, const int* in_sizes, int n_in,
                              void* d_out, int out_size, void* d_ws, size_t ws_size,
                              hipStream_t stream) {
    (void)n_in; (void)out_size; (void)ws_size;
    const float* preds = (const float*)d_in[0];
    const float* tgt   = (const float*)d_in[1];
    int N = in_sizes[1] / 6;
    if (N > NMAX) N = NMAX;

    float4* partials = (float4*)d_ws;            // (mblk+OBB) float4s
    int mblk   = (N * 15 + WPB - 1) / WPB;       // 480 for N=256
    int totblk = mblk + OBB;                     // 555

    k_main<<<totblk, 512, 0, stream>>>(preds, tgt, N, mblk, partials);
    k_final<<<1, 256, 0, stream>>>(partials, totblk, (float*)d_out);
}